// Round 3
// baseline (188.295 us; speedup 1.0000x reference)
//
#include <hip/hip_runtime.h>

// element_mars[nids, :] = node_mars[cids, :, :].sum(axis=1)
// N=500000, P=500000, C=4, B=128, E=P+1 (row 0 dummy, copied from input)
//
// Each thread handles one float4 column (q in [0,32)) of FOUR consecutive
// output rows: batches the index loads and puts 16 independent row-gathers
// in flight (MLP on the cids->gather dependent chain).
//
// Output is write-once / never re-read -> nontemporal stores, so the 256 MB
// write stream does not evict node_mars (256 MB, ~4x reuse) from the 256 MB
// Infinity Cache. Targets the ~250 MB of observed HBM read re-fetch.
//
// NOTE: __builtin_nontemporal_store needs a NATIVE clang vector type, not
// HIP's float4 class -> use ext_vector_type(4).

typedef float  v4f __attribute__((ext_vector_type(4)));
typedef int    v4i __attribute__((ext_vector_type(4)));

#define RPT 4  // rows per thread

__global__ __launch_bounds__(256) void ProdLayer_15942918602882_kernel(
    const v4f* __restrict__ nm,    // node_mars  [N][32] as v4f
    const v4f* __restrict__ em,    // element_mars input [E][32] as v4f
    const int* __restrict__ nids,  // [P]
    const v4i* __restrict__ cids,  // [P] (C=4 packed)
    v4f*       __restrict__ out,   // [E][32] as v4f
    int P)
{
    int gid = blockIdx.x * blockDim.x + threadIdx.x;
    int g = gid >> 5;          // row-group id
    int q = gid & 31;          // v4f column within the 128-float row
    int r0 = g * RPT;          // first output row of this group
    if (r0 > P) return;

    // Batch the index loads (independent, issue together).
    v4i c[RPT];
    int nid[RPT];
#pragma unroll
    for (int k = 0; k < RPT; ++k) {
        int r = r0 + k;
        if (r >= 1 && r <= P) {
            c[k]   = cids[r - 1];
            nid[k] = nids[r - 1];
        } else {
            nid[k] = -1;
        }
    }

#pragma unroll
    for (int k = 0; k < RPT; ++k) {
        int r = r0 + k;
        if (r == 0) {
            // dummy row 0: pass through the element_mars input
            __builtin_nontemporal_store(em[q], &out[q]);
            continue;
        }
        if (r > P) continue;
        v4f a = nm[(size_t)c[k].x * 32 + q];
        v4f b = nm[(size_t)c[k].y * 32 + q];
        v4f d = nm[(size_t)c[k].z * 32 + q];
        v4f e = nm[(size_t)c[k].w * 32 + q];
        v4f s = (a + b) + (d + e);
        __builtin_nontemporal_store(s, &out[(size_t)nid[k] * 32 + q]);
    }
}

extern "C" void kernel_launch(void* const* d_in, const int* in_sizes, int n_in,
                              void* d_out, int out_size, void* d_ws, size_t ws_size,
                              hipStream_t stream) {
    const v4f* nm   = (const v4f*)d_in[0];  // node_mars    [N*128] f32
    const v4f* em   = (const v4f*)d_in[1];  // element_mars [E*128] f32
    const int* nids = (const int*)d_in[2];  // [P] int32
    const v4i* cids = (const v4i*)d_in[3];  // [P*4] int32
    v4f*       out  = (v4f*)d_out;          // [E*128] f32

    const int P = in_sizes[2];              // 500000
    const long long groups = ((long long)P + 1 + RPT - 1) / RPT;
    const long long items  = groups * 32;
    const int block = 256;
    const int grid  = (int)((items + block - 1) / block);

    ProdLayer_15942918602882_kernel<<<grid, block, 0, stream>>>(
        nm, em, nids, cids, out, P);
}

// Round 4
// 176.664 us; speedup vs baseline: 1.0658x; 1.0658x over previous
//
#include <hip/hip_runtime.h>

// element_mars[nids, :] = node_mars[cids, :, :].sum(axis=1)
// N=500000, P=500000, C=4, B=128, E=P+1 (row 0 dummy, copied from input)
//
// Mapping (best measured): thread = (output row r, float4-col q in [0,32)).
// A wave's 64 lanes cover rows {g, g+1} -> every gather/store instruction
// touches two contiguous 512B rows (1KB span for the store stream, which is
// sequential since nids is 1..P). RPT>1 variants split this span (-6%, R3).
//
// NT stores were tried (R3): FETCH unchanged (Infinity Cache is memory-side,
// write traffic allocates regardless of the nt hint) -> dropped.

typedef float v4f __attribute__((ext_vector_type(4)));
typedef int   v4i __attribute__((ext_vector_type(4)));

__global__ __launch_bounds__(256) void ProdLayer_15942918602882_kernel(
    const v4f* __restrict__ nm,    // node_mars  [N][32] as v4f
    const v4f* __restrict__ em,    // element_mars input [E][32] as v4f
    const int* __restrict__ nids,  // [P]
    const v4i* __restrict__ cids,  // [P] (C=4 packed)
    v4f*       __restrict__ out,   // [E][32] as v4f
    int P)
{
    int gid = blockIdx.x * blockDim.x + threadIdx.x;
    int r = gid >> 5;        // output row: 0..P
    int q = gid & 31;        // float4 column within the 128-float row
    if (r > P) return;

    if (r == 0) {
        // dummy row 0: pass through the element_mars input
        out[q] = em[q];
        return;
    }

    int p = r - 1;
    v4i c = cids[p];         // 4 child row indices (1-based into node_mars)
    int n = nids[p];
    v4f a = nm[(size_t)c.x * 32 + q];
    v4f b = nm[(size_t)c.y * 32 + q];
    v4f d = nm[(size_t)c.z * 32 + q];
    v4f e = nm[(size_t)c.w * 32 + q];

    out[(size_t)n * 32 + q] = (a + b) + (d + e);
}

extern "C" void kernel_launch(void* const* d_in, const int* in_sizes, int n_in,
                              void* d_out, int out_size, void* d_ws, size_t ws_size,
                              hipStream_t stream) {
    const v4f* nm   = (const v4f*)d_in[0];  // node_mars    [N*128] f32
    const v4f* em   = (const v4f*)d_in[1];  // element_mars [E*128] f32
    const int* nids = (const int*)d_in[2];  // [P] int32
    const v4i* cids = (const v4i*)d_in[3];  // [P*4] int32
    v4f*       out  = (v4f*)d_out;          // [E*128] f32

    const int P = in_sizes[2];              // 500000
    const long long items = (long long)(P + 1) * 32;
    const int block = 256;
    const int grid  = (int)((items + block - 1) / block);

    ProdLayer_15942918602882_kernel<<<grid, block, 0, stream>>>(
        nm, em, nids, cids, out, P);
}